// Round 1
// baseline (429.125 us; speedup 1.0000x reference)
//
#include <hip/hip_runtime.h>

#define NPATH 4864
#define YDIM  25
#define NW    259
#define NCG   1225

// ---------------- compile-time CG tables ----------------

struct Tables {
    float cg[NCG];   // per-combo flattened [a][b][c] CG tensors, unit Frobenius norm
    int   woff[NW];  // W decode: cg row offset
    int   wlf[NW];   // W decode: l_filter
    int   wij[NW];   // W decode: (i*3+j) norm-coef index
};

constexpr double cfact(int n) { double f = 1.0; for (int i = 2; i <= n; ++i) f *= (double)i; return f; }

constexpr double csqrt_(double x) {
    if (x <= 0.0) return 0.0;
    double g = x > 1.0 ? x : 1.0, p = 0.0;
    for (int it = 0; it < 200; ++it) { p = g; g = 0.5 * (g + x / g); if (g == p) break; }
    return g;
}
constexpr int cabs_(int x) { return x < 0 ? -x : x; }
constexpr int cmax3(int a, int b, int c) { int m = a > b ? a : b; return m > c ? m : c; }
constexpr int cmin3(int a, int b, int c) { int m = a < b ? a : b; return m < c ? m : c; }

constexpr double cwig3j(int j1, int j2, int j3, int m1, int m2, int m3) {
    if (m1 + m2 + m3 != 0) return 0.0;
    if (cabs_(m1) > j1 || cabs_(m2) > j2 || cabs_(m3) > j3) return 0.0;
    if (j3 < cabs_(j1 - j2) || j3 > j1 + j2) return 0.0;
    double prod = cfact(j1 + j2 - j3) * cfact(j1 - j2 + j3) * cfact(-j1 + j2 + j3)
                / cfact(j1 + j2 + j3 + 1);
    prod *= cfact(j1 + m1) * cfact(j1 - m1) * cfact(j2 + m2) * cfact(j2 - m2)
          * cfact(j3 + m3) * cfact(j3 - m3);
    double pre = csqrt_(prod);
    int t0 = cmax3(0, j2 - j3 - m1, j1 - j3 + m2);
    int t1 = cmin3(j1 + j2 - j3, j1 - m1, j2 + m2);
    double s = 0.0;
    for (int t = t0; t <= t1; ++t) {
        double d = cfact(t) * cfact(j3 - j2 + m1 + t) * cfact(j3 - j1 - m2 + t)
                 * cfact(j1 + j2 - j3 - t) * cfact(j1 - m1 - t) * cfact(j2 + m2 - t);
        s += ((t & 1) ? -1.0 : 1.0) / d;
    }
    int p = j1 - j2 - m3; p = ((p % 2) + 2) % 2;
    return (p ? -1.0 : 1.0) * pre * s;
}

struct Ent { int col; double re; double im; };

// Row a of real_to_complex(l): complex Y^M (M=a-l) in the real basis; <=2 nonzeros.
constexpr int arow(int l, int a, Ent* e) {
    int m = a - l;
    double s2 = csqrt_(0.5);
    if (m == 0) { e[0] = Ent{l, 1.0, 0.0}; return 1; }
    if (m > 0) {
        double sgn = (m & 1) ? -1.0 : 1.0;
        e[0] = Ent{l + m, sgn * s2, 0.0};
        e[1] = Ent{l - m, 0.0, sgn * s2};
        return 2;
    }
    int mm = -m;
    e[0] = Ent{l + mm, s2, 0.0};
    e[1] = Ent{l - mm, 0.0, -s2};
    return 2;
}

constexpr Tables make_tables() {
    Tables T{};
    const int CL1[19]  = {0,0,0,1,1,1,1,1,1,1,2,2,2,2,2,2,2,2,2};
    const int CL2[19]  = {0,1,2,0,1,1,1,2,2,2,0,1,1,1,2,2,2,2,2};
    const int CL3[19]  = {0,1,2,1,0,1,2,1,2,3,2,1,2,3,0,1,2,3,4};
    const int COFF[19] = {0,1,10,35,44,53,80,125,170,245,350,375,420,495,600,625,700,825,1000};

    for (int c = 0; c < 19; ++c) {
        int l1 = CL1[c], l2 = CL2[c], l3 = CL3[c], coff = COFF[c];
        int n1 = 2 * l1 + 1, n2 = 2 * l2 + 1, n3 = 2 * l3 + 1, ntot = n1 * n2 * n3;
        double Cre[225] = {}, Cim[225] = {};
        for (int a = 0; a < n1; ++a)
            for (int b = 0; b < n2; ++b) {
                int m1 = a - l1, m2 = b - l2, m3 = -(m1 + m2);
                if (cabs_(m3) > l3) continue;
                double tv = cwig3j(l1, l2, l3, m1, m2, m3);
                if (tv == 0.0) continue;
                int crow = m3 + l3;
                Ent e1[2] = {}, e2[2] = {}, e3[2] = {};
                int k1 = arow(l1, a, e1), k2 = arow(l2, b, e2), k3 = arow(l3, crow, e3);
                for (int x = 0; x < k1; ++x)
                    for (int y = 0; y < k2; ++y)
                        for (int w = 0; w < k3; ++w) {
                            double r1 = e1[x].re, i1 = -e1[x].im;   // conj
                            double r2 = e2[y].re, i2 = -e2[y].im;
                            double r3 = e3[w].re, i3 = -e3[w].im;
                            double pr = r1 * r2 - i1 * i2, pi = r1 * i2 + i1 * r2;
                            double qr = pr * r3 - pi * i3, qi = pr * i3 + pi * r3;
                            int idx = (e1[x].col * n2 + e2[y].col) * n3 + e3[w].col;
                            Cre[idx] += tv * qr;
                            Cim[idx] += tv * qi;
                        }
            }
        double sR = 0.0, sI = 0.0;
        for (int i = 0; i < ntot; ++i) { sR += Cre[i] * Cre[i]; sI += Cim[i] * Cim[i]; }
        bool useRe = (sR >= sI);
        double nn = csqrt_(useRe ? sR : sI);
        double inv = nn > 0.0 ? 1.0 / nn : 0.0;
        for (int i = 0; i < ntot; ++i)
            T.cg[coff + i] = (float)((useRe ? Cre[i] : Cim[i]) * inv);
    }

    // W decode table: flat w -> (cg row offset, lf, ij). Matches W layout order.
    const int NLFt[9]   = {1,1,1,1,3,3,1,3,5};
    const int CGOFF9[9] = {0,1,10,35,44,125,350,375,600};
    int w = 0;
    for (int ij = 0; ij < 9; ++ij) {
        int lo = ij / 3, li = ij % 3;
        int lfmin = lo > li ? lo - li : li - lo;
        int no2 = 2 * lo + 1, ni2 = 2 * li + 1, cgo = CGOFF9[ij];
        for (int k = 0; k < NLFt[ij]; ++k) {
            int lf = lfmin + k;
            for (int a = 0; a < no2; ++a)
                for (int b = 0; b < ni2; ++b) {
                    T.woff[w] = cgo + (a * ni2 + b) * (2 * lf + 1);
                    T.wlf[w]  = lf;
                    T.wij[w]  = ij;
                    ++w;
                }
            cgo += no2 * ni2 * (2 * lf + 1);
        }
    }
    return T;
}

constexpr Tables H_TAB = make_tables();
__device__ __constant__ Tables d_tab = H_TAB;

// ---------------- region compute: one (l_out=I, l_in=J) block ----------------
// Thread owns a 4-column quad (float4 store) and a u-subrange; W cached in regs.
// Work shape: NCQ column-quads x NO2 a-rows x S u-slices = NT threads, UL=16/S u-iters.
template <int I, int J, int NLF, int NCQ, int S,
          int WBASE, int ROFF, int ROWB, int COLB>
__device__ __forceinline__ void region(const float* __restrict__ Wl,
                                       const float* __restrict__ Rl,
                                       float* __restrict__ Oz, int t) {
    constexpr int NO2 = 2 * I + 1, NI2 = 2 * J + 1;
    constexpr int NT  = NCQ * NO2 * S;
    constexpr int UL  = 16 / S;
    if (t >= NT) return;

    int c  = t % NCQ;              // column-quad within block
    int a  = (t / NCQ) % NO2;      // output row within u-group
    int us = t / (NCQ * NO2);      // u-slice

    float Wreg[NLF][4];
    int rb[4];
#pragma unroll
    for (int cc = 0; cc < 4; ++cc) {
        int cl = 4 * c + cc;       // local column in this j-block
        int v  = cl / NI2;
        int b  = cl - v * NI2;
        rb[cc] = ROFF + v * NLF;
#pragma unroll
        for (int k = 0; k < NLF; ++k)
            Wreg[k][cc] = Wl[WBASE + (k * NO2 + a) * NI2 + b];
    }

    float* obase = Oz + (ROWB + a) * 144 + COLB + 4 * c;
#pragma unroll
    for (int uu = 0; uu < UL; ++uu) {
        int u   = us * UL + uu;
        int rbu = u * 16 * NLF;
        float acc0 = 0.f, acc1 = 0.f, acc2 = 0.f, acc3 = 0.f;
#pragma unroll
        for (int k = 0; k < NLF; ++k) {
            acc0 += Wreg[k][0] * Rl[rb[0] + rbu + k];
            acc1 += Wreg[k][1] * Rl[rb[1] + rbu + k];
            acc2 += Wreg[k][2] * Rl[rb[2] + rbu + k];
            acc3 += Wreg[k][3] * Rl[rb[3] + rbu + k];
        }
        *(float4*)(obase + u * NO2 * 144) = make_float4(acc0, acc1, acc2, acc3);
    }
}

// ---------------- main tensor-product kernel ----------------

__global__ __launch_bounds__(256) void tp_kernel(const float* __restrict__ Yg,
                                                 const float* __restrict__ Rg,
                                                 const float* __restrict__ Ng,
                                                 float* __restrict__ Og, int batch) {
    __shared__ __align__(16) float Rl[NPATH];
    __shared__ float Wl[NW];
    __shared__ float Ys[YDIM];
    __shared__ float Ns[9];

    int z = blockIdx.x;
    int t = threadIdx.x;

    // Stage R[z,:] coalesced as float4 (19456 B row, 16B-aligned).
    const float4* Rg4 = (const float4*)(Rg + (size_t)z * NPATH);
    float4* Rl4 = (float4*)Rl;
    for (int p = t; p < NPATH / 4; p += 256) Rl4[p] = Rg4[p];
    if (t < YDIM) Ys[t] = Yg[t * batch + z];                 // Y is [25, batch]
    if (t >= 32 && t < 41) Ns[t - 32] = Ng[(t - 32) * batch + z];  // norm [3,3,batch]
    __syncthreads();

    // W[w] = norm(ij) * sum_c cg[row_w, c] * Y[lf^2 + c, z]   (259 values)
    for (int w = t; w < NW; w += 256) {
        int off = d_tab.woff[w], lf = d_tab.wlf[w];
        float acc = 0.f;
        for (int ci = 0; ci <= 2 * lf; ++ci) acc += d_tab.cg[off + ci] * Ys[lf * lf + ci];
        Wl[w] = acc * Ns[d_tab.wij[w]];
    }
    __syncthreads();

    float* Oz = Og + (size_t)z * 20736;

    // 9 disjoint output regions, largest first. No barriers needed between them.
    //      I  J NLF NCQ  S   WB    RO  RB  CB
    region<2, 2, 5, 20, 2, 134, 3584, 64, 64>(Wl, Rl, Oz, t);  // NT=200, UL=8
    region<2, 1, 3, 12, 4,  89, 2816, 64, 16>(Wl, Rl, Oz, t);  // NT=240, UL=4
    region<1, 2, 3, 20, 4,  39, 1792, 16, 64>(Wl, Rl, Oz, t);  // NT=240, UL=4
    region<1, 1, 3, 12, 4,  12, 1024, 16, 16>(Wl, Rl, Oz, t);  // NT=144, UL=4
    region<2, 0, 1,  4, 8,  84, 2560, 64,  0>(Wl, Rl, Oz, t);  // NT=160, UL=2
    region<0, 2, 1, 20, 8,   4,  512,  0, 64>(Wl, Rl, Oz, t);  // NT=160, UL=2
    region<1, 0, 1,  4,16,   9,  768, 16,  0>(Wl, Rl, Oz, t);  // NT=192, UL=1
    region<0, 1, 1, 12,16,   1,  256,  0, 16>(Wl, Rl, Oz, t);  // NT=192, UL=1
    region<0, 0, 1,  4,16,   0,    0,  0,  0>(Wl, Rl, Oz, t);  // NT=64,  UL=1
}

extern "C" void kernel_launch(void* const* d_in, const int* in_sizes, int n_in,
                              void* d_out, int out_size, void* d_ws, size_t ws_size,
                              hipStream_t stream) {
    const float* Y = (const float*)d_in[0];
    const float* R = (const float*)d_in[1];
    const float* N = (const float*)d_in[2];
    float* O = (float*)d_out;
    int batch = in_sizes[0] / YDIM;   // 4096

    hipLaunchKernelGGL(tp_kernel, dim3(batch), dim3(256), 0, stream, Y, R, N, O, batch);
}

// Round 4
// 417.089 us; speedup vs baseline: 1.0289x; 1.0289x over previous
//
#include <hip/hip_runtime.h>

#define NPATH 4864
#define YDIM  25
#define NW    259
#define NCG   1225
#define NWP   400   // padded W LDS size (floats)

// ---------------- compile-time CG tables ----------------

struct Tables {
    float cg[NCG];   // per-combo flattened [a][b][c] CG tensors, unit Frobenius norm
    int   woff[NW];  // W decode: cg row offset
    int   wlf[NW];   // W decode: l_filter
    int   wij[NW];   // W decode: (i*3+j) norm-coef index
    int   wdst[NW];  // W decode: destination in padded Wp layout
};

constexpr double cfact(int n) { double f = 1.0; for (int i = 2; i <= n; ++i) f *= (double)i; return f; }

constexpr double csqrt_(double x) {
    if (x <= 0.0) return 0.0;
    double g = x > 1.0 ? x : 1.0, p = 0.0;
    for (int it = 0; it < 200; ++it) { p = g; g = 0.5 * (g + x / g); if (g == p) break; }
    return g;
}
constexpr int cabs_(int x) { return x < 0 ? -x : x; }
constexpr int cmax3(int a, int b, int c) { int m = a > b ? a : b; return m > c ? m : c; }
constexpr int cmin3(int a, int b, int c) { int m = a < b ? a : b; return m < c ? m : c; }

constexpr double cwig3j(int j1, int j2, int j3, int m1, int m2, int m3) {
    if (m1 + m2 + m3 != 0) return 0.0;
    if (cabs_(m1) > j1 || cabs_(m2) > j2 || cabs_(m3) > j3) return 0.0;
    if (j3 < cabs_(j1 - j2) || j3 > j1 + j2) return 0.0;
    double prod = cfact(j1 + j2 - j3) * cfact(j1 - j2 + j3) * cfact(-j1 + j2 + j3)
                / cfact(j1 + j2 + j3 + 1);
    prod *= cfact(j1 + m1) * cfact(j1 - m1) * cfact(j2 + m2) * cfact(j2 - m2)
          * cfact(j3 + m3) * cfact(j3 - m3);
    double pre = csqrt_(prod);
    int t0 = cmax3(0, j2 - j3 - m1, j1 - j3 + m2);
    int t1 = cmin3(j1 + j2 - j3, j1 - m1, j2 + m2);
    double s = 0.0;
    for (int t = t0; t <= t1; ++t) {
        double d = cfact(t) * cfact(j3 - j2 + m1 + t) * cfact(j3 - j1 - m2 + t)
                 * cfact(j1 + j2 - j3 - t) * cfact(j1 - m1 - t) * cfact(j2 + m2 - t);
        s += ((t & 1) ? -1.0 : 1.0) / d;
    }
    int p = j1 - j2 - m3; p = ((p % 2) + 2) % 2;
    return (p ? -1.0 : 1.0) * pre * s;
}

struct Ent { int col; double re; double im; };

// Row a of real_to_complex(l): complex Y^M (M=a-l) in the real basis; <=2 nonzeros.
constexpr int arow(int l, int a, Ent* e) {
    int m = a - l;
    double s2 = csqrt_(0.5);
    if (m == 0) { e[0] = Ent{l, 1.0, 0.0}; return 1; }
    if (m > 0) {
        double sgn = (m & 1) ? -1.0 : 1.0;
        e[0] = Ent{l + m, sgn * s2, 0.0};
        e[1] = Ent{l - m, 0.0, sgn * s2};
        return 2;
    }
    int mm = -m;
    e[0] = Ent{l + mm, s2, 0.0};
    e[1] = Ent{l - mm, 0.0, -s2};
    return 2;
}

constexpr Tables make_tables() {
    Tables T{};
    const int CL1[19]  = {0,0,0,1,1,1,1,1,1,1,2,2,2,2,2,2,2,2,2};
    const int CL2[19]  = {0,1,2,0,1,1,1,2,2,2,0,1,1,1,2,2,2,2,2};
    const int CL3[19]  = {0,1,2,1,0,1,2,1,2,3,2,1,2,3,0,1,2,3,4};
    const int COFF[19] = {0,1,10,35,44,53,80,125,170,245,350,375,420,495,600,625,700,825,1000};

    for (int c = 0; c < 19; ++c) {
        int l1 = CL1[c], l2 = CL2[c], l3 = CL3[c], coff = COFF[c];
        int n1 = 2 * l1 + 1, n2 = 2 * l2 + 1, n3 = 2 * l3 + 1, ntot = n1 * n2 * n3;
        double Cre[225] = {}, Cim[225] = {};
        for (int a = 0; a < n1; ++a)
            for (int b = 0; b < n2; ++b) {
                int m1 = a - l1, m2 = b - l2, m3 = -(m1 + m2);
                if (cabs_(m3) > l3) continue;
                double tv = cwig3j(l1, l2, l3, m1, m2, m3);
                if (tv == 0.0) continue;
                int crow = m3 + l3;
                Ent e1[2] = {}, e2[2] = {}, e3[2] = {};
                int k1 = arow(l1, a, e1), k2 = arow(l2, b, e2), k3 = arow(l3, crow, e3);
                for (int x = 0; x < k1; ++x)
                    for (int y = 0; y < k2; ++y)
                        for (int w = 0; w < k3; ++w) {
                            double r1 = e1[x].re, i1 = -e1[x].im;   // conj
                            double r2 = e2[y].re, i2 = -e2[y].im;
                            double r3 = e3[w].re, i3 = -e3[w].im;
                            double pr = r1 * r2 - i1 * i2, pi = r1 * i2 + i1 * r2;
                            double qr = pr * r3 - pi * i3, qi = pr * i3 + pi * r3;
                            int idx = (e1[x].col * n2 + e2[y].col) * n3 + e3[w].col;
                            Cre[idx] += tv * qr;
                            Cim[idx] += tv * qi;
                        }
            }
        double sR = 0.0, sI = 0.0;
        for (int i = 0; i < ntot; ++i) { sR += Cre[i] * Cre[i]; sI += Cim[i] * Cim[i]; }
        bool useRe = (sR >= sI);
        double nn = csqrt_(useRe ? sR : sI);
        double inv = nn > 0.0 ? 1.0 / nn : 0.0;
        for (int i = 0; i < ntot; ++i)
            T.cg[coff + i] = (float)((useRe ? Cre[i] : Cim[i]) * inv);
    }

    // W decode table: flat w -> (cg row offset, lf, ij, padded dst). Matches W layout order.
    const int NLFt[9]   = {1,1,1,1,3,3,1,3,5};
    const int CGOFF9[9] = {0,1,10,35,44,125,350,375,600};
    // Padded Wp layout: per-region rows (k,a) padded to PAD floats so NI2=3/5 rows
    // are one aligned b128 (+b32) broadcast. Bases chosen 16B/32B aligned.
    const int WPB[9]  = {0, 4, 8, 16, 20, 56, 128, 136, 200};
    const int PADt[9] = {1, 4, 8,  1,  4,  8,   1,   4,   8};   // by li = ij%3
    int w = 0;
    for (int ij = 0; ij < 9; ++ij) {
        int lo = ij / 3, li = ij % 3;
        int lfmin = lo > li ? lo - li : li - lo;
        int no2 = 2 * lo + 1, ni2 = 2 * li + 1, cgo = CGOFF9[ij];
        for (int k = 0; k < NLFt[ij]; ++k) {
            int lf = lfmin + k;
            for (int a = 0; a < no2; ++a)
                for (int b = 0; b < ni2; ++b) {
                    T.woff[w] = cgo + (a * ni2 + b) * (2 * lf + 1);
                    T.wlf[w]  = lf;
                    T.wij[w]  = ij;
                    T.wdst[w] = WPB[ij] + (k * no2 + a) * PADt[ij] + b;
                    ++w;
                }
            cgo += no2 * ni2 * (2 * lf + 1);
        }
    }
    return T;
}

constexpr Tables H_TAB = make_tables();
__device__ __constant__ Tables d_tab = H_TAB;

// ---------------- region compute ----------------
// Thread owns one (u,v) cell and computes ALL (a,b) outputs of the region.
// R reads: NLF scalars (stride NLF across lanes -> conflict-free).
// W reads: wave-uniform addresses -> LDS broadcast; padded rows -> b128.
template <int I, int J, int NLF, int WPB, int PAD, int ROFF, int ROWB, int COLB>
__device__ __forceinline__ void region(const float* __restrict__ Wp,
                                       const float* __restrict__ Rl,
                                       float* __restrict__ Oz, int u, int v) {
    constexpr int NO2 = 2 * I + 1, NI2 = 2 * J + 1;
    const float* rb = Rl + ROFF + (u * 16 + v) * NLF;
    float Rk[NLF];
#pragma unroll
    for (int k = 0; k < NLF; ++k) Rk[k] = rb[k];

    float acc[NO2][NI2];
#pragma unroll
    for (int a = 0; a < NO2; ++a)
#pragma unroll
        for (int b = 0; b < NI2; ++b) acc[a][b] = 0.f;

#pragma unroll
    for (int k = 0; k < NLF; ++k)
#pragma unroll
        for (int a = 0; a < NO2; ++a) {
            const float* wrow = Wp + WPB + (k * NO2 + a) * PAD;
            if constexpr (NI2 == 1) {
                acc[a][0] += wrow[0] * Rk[k];
            } else if constexpr (NI2 == 3) {
                float4 w4 = *(const float4*)wrow;   // aligned b128 broadcast
                acc[a][0] += w4.x * Rk[k];
                acc[a][1] += w4.y * Rk[k];
                acc[a][2] += w4.z * Rk[k];
            } else {
                float4 w4 = *(const float4*)wrow;   // aligned b128 broadcast
                float  w5 = wrow[4];
                acc[a][0] += w4.x * Rk[k];
                acc[a][1] += w4.y * Rk[k];
                acc[a][2] += w4.z * Rk[k];
                acc[a][3] += w4.w * Rk[k];
                acc[a][4] += w5   * Rk[k];
            }
        }

    float* ob = Oz + (ROWB + u * NO2) * 144 + COLB + v * NI2;
#pragma unroll
    for (int a = 0; a < NO2; ++a)
#pragma unroll
        for (int b = 0; b < NI2; ++b) ob[a * 144 + b] = acc[a][b];
}

// ---------------- main tensor-product kernel ----------------

__global__ __launch_bounds__(256) void tp_kernel(const float* __restrict__ Yg,
                                                 const float* __restrict__ Rg,
                                                 const float* __restrict__ Ng,
                                                 float* __restrict__ Og, int batch) {
    __shared__ __align__(16) float Rl[NPATH];
    __shared__ __align__(16) float Wp[NWP];
    __shared__ float Ys[YDIM];
    __shared__ float Ns[9];

    int z = blockIdx.x;
    int t = threadIdx.x;

    // Stage R[z,:] coalesced as float4 (19456 B row, 16B-aligned).
    const float4* Rg4 = (const float4*)(Rg + (size_t)z * NPATH);
    float4* Rl4 = (float4*)Rl;
    for (int p = t; p < NPATH / 4; p += 256) Rl4[p] = Rg4[p];
    if (t < YDIM) Ys[t] = Yg[t * batch + z];                       // Y is [25, batch]
    if (t >= 32 && t < 41) Ns[t - 32] = Ng[(t - 32) * batch + z];  // norm [3,3,batch]
    __syncthreads();

    // W[w] = norm(ij) * sum_c cg[row_w, c] * Y[lf^2 + c, z]; scatter into padded Wp.
    for (int w = t; w < NW; w += 256) {
        int off = d_tab.woff[w], lf = d_tab.wlf[w];
        float acc = 0.f;
        for (int ci = 0; ci <= 2 * lf; ++ci) acc += d_tab.cg[off + ci] * Ys[lf * lf + ci];
        Wp[d_tab.wdst[w]] = acc * Ns[d_tab.wij[w]];
    }
    __syncthreads();

    float* Oz = Og + (size_t)z * 20736;
    int u = t >> 4, v = t & 15;   // 256 threads = 16x16 (u,v) cells

    // 9 disjoint output regions; every thread computes its full (u,v) micro-tile.
    //      I  J NLF  WPB PAD  ROFF  RB  CB
    region<0, 0, 1,   0, 1,     0,  0,  0>(Wp, Rl, Oz, u, v);
    region<0, 1, 1,   4, 4,   256,  0, 16>(Wp, Rl, Oz, u, v);
    region<0, 2, 1,   8, 8,   512,  0, 64>(Wp, Rl, Oz, u, v);
    region<1, 0, 1,  16, 1,   768, 16,  0>(Wp, Rl, Oz, u, v);
    region<1, 1, 3,  20, 4,  1024, 16, 16>(Wp, Rl, Oz, u, v);
    region<1, 2, 3,  56, 8,  1792, 16, 64>(Wp, Rl, Oz, u, v);
    region<2, 0, 1, 128, 1,  2560, 64,  0>(Wp, Rl, Oz, u, v);
    region<2, 1, 3, 136, 4,  2816, 64, 16>(Wp, Rl, Oz, u, v);
    region<2, 2, 5, 200, 8,  3584, 64, 64>(Wp, Rl, Oz, u, v);
}

extern "C" void kernel_launch(void* const* d_in, const int* in_sizes, int n_in,
                              void* d_out, int out_size, void* d_ws, size_t ws_size,
                              hipStream_t stream) {
    const float* Y = (const float*)d_in[0];
    const float* R = (const float*)d_in[1];
    const float* N = (const float*)d_in[2];
    float* O = (float*)d_out;
    int batch = in_sizes[0] / YDIM;   // 4096

    hipLaunchKernelGGL(tp_kernel, dim3(batch), dim3(256), 0, stream, Y, R, N, O, batch);
}